// Round 1
// baseline (494.575 us; speedup 1.0000x reference)
//
#include <hip/hip_runtime.h>
#include <hip/hip_bf16.h>
#include <stdint.h>

#define B_ 1024
#define N_ 128
#define D_ 128
#define H_ 256
#define L_ 64
#define INF_ 0x3FFFFFFF

__device__ __forceinline__ float b2f(uint16_t u) {
    return __uint_as_float(((uint32_t)u) << 16);
}
__device__ __forceinline__ uint16_t f2b(float f) {
    uint32_t u = __float_as_uint(f);
    uint32_t r = (u + 0x7FFFu + ((u >> 16) & 1u)) >> 16;   // RNE
    return (uint16_t)r;
}
__device__ __forceinline__ void unpack4(uint64_t w, float* f) {
    f[0] = b2f((uint16_t)w);
    f[1] = b2f((uint16_t)(w >> 16));
    f[2] = b2f((uint16_t)(w >> 32));
    f[3] = b2f((uint16_t)(w >> 48));
}
__device__ __forceinline__ uint64_t pack4(float a, float b, float c, float d) {
    return (uint64_t)f2b(a) | ((uint64_t)f2b(b) << 16) |
           ((uint64_t)f2b(c) << 32) | ((uint64_t)f2b(d) << 48);
}

__global__ __launch_bounds__(256, 2) void tree_encoder_kernel(
    const float* __restrict__ x, const float* __restrict__ adj,
    const float* __restrict__ W1, const float* __restrict__ b1,
    const float* __restrict__ W2, const float* __restrict__ b2,
    const float* __restrict__ Wmu, const float* __restrict__ bmu,
    const float* __restrict__ Wlv, const float* __restrict__ blv,
    float* __restrict__ out)
{
    // big buffer: phase A = {x bf16 [128][128] | xa bf16 [128][128]},
    // phase B = h1 bf16 [128][256], phase C = M2 bf16 [128][256]
    __shared__ uint16_t sbuf[32768];          // 64 KB
    __shared__ uint32_t adjm[128][4];         // adjacency bitmasks
    __shared__ uint32_t tnbr[128][4];         // tree-neighbor bitmasks
    __shared__ int      s_order[128];
    __shared__ int      s_parent[128];
    __shared__ int      s_key[128];
    __shared__ float    s_invdeg[128];
    __shared__ uint32_t visw[4];
    __shared__ uint32_t actw[4];
    __shared__ int      s_root;
    __shared__ float    s_g[256];

    const int tid = threadIdx.x;
    const int b   = blockIdx.x;
    const float* xg = x   + (size_t)b * N_ * D_;
    const float* ag = adj + (size_t)b * N_ * N_;

    // ---------- init small state ----------
    if (tid < 128) { s_order[tid] = INF_; s_parent[tid] = 0; }
    if (tid < 4)   { visw[tid] = 0u; actw[tid] = 0u; }
    if (tid == 0)  { s_root = 128; }

    // ---------- load x -> bf16 LDS [0..16384) ----------
    {
        const float4* xg4 = reinterpret_cast<const float4*>(xg);
        #pragma unroll
        for (int i = 0; i < 16; ++i) {
            int idx = tid + i * 256;                  // 4096 float4 total
            float4 v = xg4[idx];
            *reinterpret_cast<uint64_t*>(&sbuf[idx * 4]) =
                pack4(v.x, v.y, v.z, v.w);
        }
    }
    // ---------- load adj -> bitmasks ----------
    {
        const int v = tid >> 1, half = tid & 1;
        const float4* ag4 = reinterpret_cast<const float4*>(ag + v * N_ + half * 64);
        uint32_t w0 = 0, w1 = 0;
        #pragma unroll
        for (int i = 0; i < 16; ++i) {
            float4 f = ag4[i];
            uint32_t bs = (f.x > 0.5f ? 1u : 0u) | (f.y > 0.5f ? 2u : 0u) |
                          (f.z > 0.5f ? 4u : 0u) | (f.w > 0.5f ? 8u : 0u);
            int base = i * 4;
            if (base < 32) w0 |= bs << base; else w1 |= bs << (base - 32);
        }
        adjm[v][half * 2]     = w0;
        adjm[v][half * 2 + 1] = w1;
    }
    __syncthreads();

    // ---------- active nodes + root = first active ----------
    if (tid < 128) {
        uint32_t any = adjm[tid][0] | adjm[tid][1] | adjm[tid][2] | adjm[tid][3];
        if (any) {
            atomicMin(&s_root, tid);
            atomicOr(&actw[tid >> 5], 1u << (tid & 31));
        }
    }
    __syncthreads();

    int counter = 0;
    if (s_root < 128) {
        if (tid == 0) {
            s_order[s_root] = 0;
            atomicOr(&visw[s_root >> 5], 1u << (s_root & 31));
        }
        counter = 1;
    }
    __syncthreads();

    // ---------- level-synchronous FIFO BFS ----------
    for (int step = 0; step < N_ - 1; ++step) {
        int newly = 0, po = INF_, par = 0;
        if (tid < 128) {
            if (s_order[tid] >= INF_) {
                #pragma unroll
                for (int w = 0; w < 4; ++w) {
                    uint32_t m = adjm[tid][w] & visw[w];
                    while (m) {
                        int u = (w << 5) + __ffs(m) - 1; m &= m - 1;
                        int o = s_order[u];
                        if (o < po) { po = o; par = u; }   // unique orders: first strict min
                    }
                }
                newly = (po < INF_);
            }
            s_key[tid] = newly ? (po * N_ + tid) : 0x7FFFFFFF;
        }
        __syncthreads();
        int myk = (tid < 128) ? s_key[tid] : 0x7FFFFFFF;
        int rank = 0, cnt = 0;
        for (int u = 0; u < 128; ++u) {
            int ku = s_key[u];
            cnt  += (ku != 0x7FFFFFFF);
            rank += (ku < myk);
        }
        if (newly) {
            s_order[tid]  = counter + rank;
            s_parent[tid] = par;
            atomicOr(&visw[tid >> 5], 1u << (tid & 31));
        }
        counter += cnt;
        __syncthreads();
        if (cnt == 0) break;
    }

    // ---------- tree neighbor masks + degrees ----------
    if (tid < 128) { tnbr[tid][0] = 0; tnbr[tid][1] = 0; tnbr[tid][2] = 0; tnbr[tid][3] = 0; }
    __syncthreads();
    if (tid < 128 && s_order[tid] > 0 && s_order[tid] < INF_) {
        int p = s_parent[tid];
        atomicOr(&tnbr[tid][p >> 5], 1u << (p & 31));
        atomicOr(&tnbr[p][tid >> 5], 1u << (tid & 31));
    }
    __syncthreads();
    if (tid < 128) {
        int d = 1 + __popc(tnbr[tid][0]) + __popc(tnbr[tid][1]) +
                    __popc(tnbr[tid][2]) + __popc(tnbr[tid][3]);
        s_invdeg[tid] = 1.0f / (float)d;
    }
    __syncthreads();

    // ---------- aggregation 1: xa = adj_norm @ x  -> sbuf[16384..32768) ----------
    {
        const int v = tid >> 1, c0 = (tid & 1) * 64;
        float acc[64];
        const uint16_t* xr = &sbuf[v * D_ + c0];
        #pragma unroll
        for (int i = 0; i < 64; i += 4) {
            uint64_t w = *reinterpret_cast<const uint64_t*>(&xr[i]);
            unpack4(w, &acc[i]);
        }
        #pragma unroll
        for (int wi = 0; wi < 4; ++wi) {
            uint32_t m = tnbr[v][wi];
            while (m) {
                int u = (wi << 5) + __ffs(m) - 1; m &= m - 1;
                const uint16_t* ur = &sbuf[u * D_ + c0];
                #pragma unroll
                for (int i = 0; i < 64; i += 4) {
                    float t[4];
                    uint64_t w = *reinterpret_cast<const uint64_t*>(&ur[i]);
                    unpack4(w, t);
                    acc[i] += t[0]; acc[i+1] += t[1]; acc[i+2] += t[2]; acc[i+3] += t[3];
                }
            }
        }
        const float inv = s_invdeg[v];
        uint16_t* xo = &sbuf[16384 + v * D_ + c0];
        #pragma unroll
        for (int i = 0; i < 64; i += 4) {
            *reinterpret_cast<uint64_t*>(&xo[i]) =
                pack4(acc[i]*inv, acc[i+1]*inv, acc[i+2]*inv, acc[i+3]*inv);
        }
    }
    __syncthreads();

    const int rt = tid >> 4, ct = tid & 15;
    const int r0 = rt * 8, c0 = ct * 16;
    float acc[128];   // 8 rows x 16 cols per thread

    // ---------- matmul1: h1 = relu(xa @ W1 + b1) -> sbuf[0..32768) ----------
    {
        #pragma unroll
        for (int i = 0; i < 128; ++i) acc[i] = 0.f;
        for (int kb = 0; kb < D_; kb += 4) {
            float a[8][4];
            #pragma unroll
            for (int i = 0; i < 8; ++i) {
                uint64_t w = *reinterpret_cast<const uint64_t*>(
                    &sbuf[16384 + (r0 + i) * D_ + kb]);
                unpack4(w, a[i]);
            }
            #pragma unroll
            for (int kk = 0; kk < 4; ++kk) {
                const float4* wr = reinterpret_cast<const float4*>(W1 + (kb + kk) * H_ + c0);
                float4 q0 = wr[0], q1 = wr[1], q2 = wr[2], q3 = wr[3];
                float wv[16] = {q0.x,q0.y,q0.z,q0.w,q1.x,q1.y,q1.z,q1.w,
                                q2.x,q2.y,q2.z,q2.w,q3.x,q3.y,q3.z,q3.w};
                #pragma unroll
                for (int i = 0; i < 8; ++i) {
                    float av = a[i][kk];
                    #pragma unroll
                    for (int j = 0; j < 16; ++j)
                        acc[i*16+j] = fmaf(av, wv[j], acc[i*16+j]);
                }
            }
        }
        __syncthreads();   // all xa reads done before overwriting buffer
        float bb[16];
        {
            const float4* b4 = reinterpret_cast<const float4*>(b1 + c0);
            float4 q0 = b4[0], q1 = b4[1], q2 = b4[2], q3 = b4[3];
            bb[0]=q0.x; bb[1]=q0.y; bb[2]=q0.z; bb[3]=q0.w;
            bb[4]=q1.x; bb[5]=q1.y; bb[6]=q1.z; bb[7]=q1.w;
            bb[8]=q2.x; bb[9]=q2.y; bb[10]=q2.z; bb[11]=q2.w;
            bb[12]=q3.x; bb[13]=q3.y; bb[14]=q3.z; bb[15]=q3.w;
        }
        #pragma unroll
        for (int i = 0; i < 8; ++i) {
            #pragma unroll
            for (int j = 0; j < 16; j += 4) {
                float v0 = fmaxf(acc[i*16+j  ] + bb[j  ], 0.f);
                float v1 = fmaxf(acc[i*16+j+1] + bb[j+1], 0.f);
                float v2 = fmaxf(acc[i*16+j+2] + bb[j+2], 0.f);
                float v3 = fmaxf(acc[i*16+j+3] + bb[j+3], 0.f);
                *reinterpret_cast<uint64_t*>(&sbuf[(r0+i)*H_ + c0 + j]) =
                    pack4(v0, v1, v2, v3);
            }
        }
        __syncthreads();
    }

    // ---------- matmul2: M2 = h1 @ W2 (bias after aggregation) -> sbuf in place ----------
    {
        #pragma unroll
        for (int i = 0; i < 128; ++i) acc[i] = 0.f;
        for (int kb = 0; kb < H_; kb += 4) {
            float a[8][4];
            #pragma unroll
            for (int i = 0; i < 8; ++i) {
                uint64_t w = *reinterpret_cast<const uint64_t*>(
                    &sbuf[(r0 + i) * H_ + kb]);
                unpack4(w, a[i]);
            }
            #pragma unroll
            for (int kk = 0; kk < 4; ++kk) {
                const float4* wr = reinterpret_cast<const float4*>(W2 + (kb + kk) * H_ + c0);
                float4 q0 = wr[0], q1 = wr[1], q2 = wr[2], q3 = wr[3];
                float wv[16] = {q0.x,q0.y,q0.z,q0.w,q1.x,q1.y,q1.z,q1.w,
                                q2.x,q2.y,q2.z,q2.w,q3.x,q3.y,q3.z,q3.w};
                #pragma unroll
                for (int i = 0; i < 8; ++i) {
                    float av = a[i][kk];
                    #pragma unroll
                    for (int j = 0; j < 16; ++j)
                        acc[i*16+j] = fmaf(av, wv[j], acc[i*16+j]);
                }
            }
        }
        __syncthreads();   // all h1 reads done
        #pragma unroll
        for (int i = 0; i < 8; ++i) {
            #pragma unroll
            for (int j = 0; j < 16; j += 4) {
                *reinterpret_cast<uint64_t*>(&sbuf[(r0+i)*H_ + c0 + j]) =
                    pack4(acc[i*16+j], acc[i*16+j+1], acc[i*16+j+2], acc[i*16+j+3]);
            }
        }
        __syncthreads();
    }

    // ---------- fused aggregation 2 + bias + relu + masked mean pool ----------
    {
        const int c = tid;                     // one column per thread
        const float bc = b2[c];
        const int num = __popc(actw[0]) + __popc(actw[1]) +
                        __popc(actw[2]) + __popc(actw[3]);
        float gacc = 0.f;
        for (int v = 0; v < 128; ++v) {
            if (!((actw[v >> 5] >> (v & 31)) & 1u)) continue;
            float s = b2f(sbuf[v * H_ + c]);
            #pragma unroll
            for (int w = 0; w < 4; ++w) {
                uint32_t m = tnbr[v][w];
                while (m) {
                    int u = (w << 5) + __ffs(m) - 1; m &= m - 1;
                    s += b2f(sbuf[u * H_ + c]);
                }
            }
            s = fmaf(s, s_invdeg[v], bc);
            gacc += fmaxf(s, 0.f);
        }
        s_g[c] = gacc / (float)(num > 0 ? num : 1);
    }
    __syncthreads();

    // ---------- heads: mu / logvar ----------
    if (tid < 128) {
        const int which = tid >> 6, l = tid & 63;
        const float* W    = which ? Wlv : Wmu;
        const float* bias = which ? blv : bmu;
        float acch = 0.f;
        for (int cc = 0; cc < H_; ++cc)
            acch = fmaf(s_g[cc], W[cc * L_ + l], acch);
        out[(size_t)which * B_ * L_ + (size_t)b * L_ + l] = acch + bias[l];
    }
}

extern "C" void kernel_launch(void* const* d_in, const int* in_sizes, int n_in,
                              void* d_out, int out_size, void* d_ws, size_t ws_size,
                              hipStream_t stream) {
    const float* x   = (const float*)d_in[0];
    const float* adj = (const float*)d_in[1];
    const float* W1  = (const float*)d_in[2];
    const float* b1  = (const float*)d_in[3];
    const float* W2  = (const float*)d_in[4];
    const float* b2  = (const float*)d_in[5];
    const float* Wmu = (const float*)d_in[6];
    const float* bmu = (const float*)d_in[7];
    const float* Wlv = (const float*)d_in[8];
    const float* blv = (const float*)d_in[9];
    float* out = (float*)d_out;

    hipLaunchKernelGGL(tree_encoder_kernel, dim3(B_), dim3(256), 0, stream,
                       x, adj, W1, b1, W2, b2, Wmu, bmu, Wlv, blv, out);
}

// Round 2
// 106.002 us; speedup vs baseline: 4.6657x; 4.6657x over previous
//
#include <hip/hip_runtime.h>
#include <stdint.h>

#define B_ 1024
#define N_ 128
#define D_ 128
#define H_ 256
#define L_ 64
#define INF_ 0x3FFFFFFF

typedef __attribute__((ext_vector_type(8))) short bf16x8;
typedef __attribute__((ext_vector_type(4))) float f32x4;
typedef __attribute__((ext_vector_type(4))) uint32_t u32x4;
typedef __attribute__((ext_vector_type(2))) uint32_t u32x2;

__device__ __forceinline__ float b2f(uint16_t u) {
    return __uint_as_float(((uint32_t)u) << 16);
}
__device__ __forceinline__ uint16_t f2b(float f) {
    uint32_t u = __float_as_uint(f);
    return (uint16_t)((u + 0x7FFFu + ((u >> 16) & 1u)) >> 16);   // RNE
}
__device__ __forceinline__ uint32_t pack2(float a, float b) {
    return (uint32_t)f2b(a) | ((uint32_t)f2b(b) << 16);
}

// ---------------- weight prep: fragment-linear bf16 layouts in ws ----------------
// ws u16 layout: [0,32768): W1T A-frags  chunk id = (tm*4+kb)*64+lane   (tm: 16 H-tiles, kb: K=128/32)
//                [32768,98304): W2 B-frags chunk id = (tn*8+kb)*64+lane (tn: 16 H-tiles, kb: K=256/32)
__global__ void prep_weights(const float* __restrict__ W1, const float* __restrict__ W2,
                             uint16_t* __restrict__ ws) {
    int t = blockIdx.x * 256 + threadIdx.x;
    if (t < 4096) {                       // W1T: A[m][k] = W1[k][m], m=h, k=f
        int lane = t & 63, fkb = t >> 6;
        int tm = fkb >> 2, kb = fkb & 3;
        int h  = tm * 16 + (lane & 15);
        int k0 = kb * 32 + (lane >> 4) * 8;
        u32x4 w;
        #pragma unroll
        for (int p = 0; p < 4; ++p)
            w[p] = pack2(W1[(k0 + 2*p) * H_ + h], W1[(k0 + 2*p + 1) * H_ + h]);
        *reinterpret_cast<u32x4*>(&ws[t * 8]) = w;
    } else if (t < 12288) {               // W2: B[k][n] = W2[k][n]
        int t2 = t - 4096;
        int lane = t2 & 63, g = t2 >> 6;
        int tn = g >> 3, kb = g & 7;
        int n  = tn * 16 + (lane & 15);
        int k0 = kb * 32 + (lane >> 4) * 8;
        u32x4 w;
        #pragma unroll
        for (int p = 0; p < 4; ++p)
            w[p] = pack2(W2[(k0 + 2*p) * H_ + n], W2[(k0 + 2*p + 1) * H_ + n]);
        *reinterpret_cast<u32x4*>(&ws[32768 + t2 * 8]) = w;
    }
}

// ---------------- main fused kernel: 1 block per graph ----------------
__global__ __launch_bounds__(256, 2) void tree_encoder_kernel(
    const float* __restrict__ x, const float* __restrict__ adj,
    const uint16_t* __restrict__ ws,
    const float* __restrict__ b1g, const float* __restrict__ b2g,
    const float* __restrict__ Wmu, const float* __restrict__ bmu,
    const float* __restrict__ Wlv, const float* __restrict__ blv,
    float* __restrict__ out)
{
    // sbuf (u16): [0,17408): x [128][136] bf16 (padded rows)
    //             [17408,33792): xa in matmul1-B-frag layout (32768 u16... region is 16384 u16)
    //             h1 frag layout overwrites [0,32768) after m1; M2 agg2-B layout in place after m2
    __shared__ __align__(16) uint16_t sbuf[33792];          // 67584 B
    __shared__ uint32_t adjm[128][4];
    __shared__ uint32_t tnbr[128][4];
    __shared__ int      s_order[128];
    __shared__ int      s_parent[128];
    __shared__ int      s_key[128];
    __shared__ float    s_inv[128];
    __shared__ float    s_wm[128];
    __shared__ float    s_b1[256];
    __shared__ float    s_b2[256];
    __shared__ float    s_g[256];
    __shared__ uint32_t visw[4], actw[4], newlyw[4];
    __shared__ int      s_root;

    const int tid  = threadIdx.x;
    const int b    = blockIdx.x;
    const int wid  = tid >> 6;
    const int lane = tid & 63;
    const int l15  = lane & 15;
    const int q    = lane >> 4;

    const float* xg = x   + (size_t)b * N_ * D_;
    const float* ag = adj + (size_t)b * N_ * N_;

    // ---------- phase 0: init + load x (bf16, padded rows) + adj bitmasks + bias staging ----------
    if (tid < 128) { s_order[tid] = INF_; s_parent[tid] = 0; }
    if (tid < 4)   { visw[tid] = 0u; actw[tid] = 0u; }
    if (tid == 0)  { s_root = 128; }
    s_b1[tid] = b1g[tid];
    s_b2[tid] = b2g[tid];
    {
        const float4* xg4 = reinterpret_cast<const float4*>(xg);
        #pragma unroll
        for (int i = 0; i < 16; ++i) {
            int idx = tid + i * 256;                 // 4096 float4
            float4 v = xg4[idx];
            int row = idx >> 5, c4 = (idx & 31) * 4;
            u32x2 w; w[0] = pack2(v.x, v.y); w[1] = pack2(v.z, v.w);
            *reinterpret_cast<u32x2*>(&sbuf[row * 136 + c4]) = w;
        }
    }
    {
        const int v = tid >> 1, hf = tid & 1;
        const float4* ag4 = reinterpret_cast<const float4*>(ag + v * N_ + hf * 64);
        uint32_t w0 = 0, w1 = 0;
        #pragma unroll
        for (int i = 0; i < 16; ++i) {
            float4 f = ag4[i];
            uint32_t bs = (f.x > 0.5f ? 1u : 0u) | (f.y > 0.5f ? 2u : 0u) |
                          (f.z > 0.5f ? 4u : 0u) | (f.w > 0.5f ? 8u : 0u);
            int base = i * 4;
            if (base < 32) w0 |= bs << base; else w1 |= bs << (base - 32);
        }
        adjm[v][hf * 2]     = w0;
        adjm[v][hf * 2 + 1] = w1;
    }
    __syncthreads();

    // ---------- active nodes + root ----------
    if (tid < 128) {
        uint32_t any = adjm[tid][0] | adjm[tid][1] | adjm[tid][2] | adjm[tid][3];
        if (any) {
            atomicMin(&s_root, tid);
            atomicOr(&actw[tid >> 5], 1u << (tid & 31));
        }
    }
    __syncthreads();
    int counter = 0;
    if (s_root < 128) {
        counter = 1;
        if (tid == 0) {
            s_order[s_root] = 0;
            visw[s_root >> 5] = 1u << (s_root & 31);
        }
    }
    __syncthreads();

    // ---------- level-synchronous FIFO BFS ----------
    for (int step = 0; step < N_ - 1; ++step) {
        if (tid < 4) newlyw[tid] = 0u;
        __syncthreads();
        int newly = 0, po = INF_, par = 0;
        if (tid < 128 && s_order[tid] >= INF_) {
            #pragma unroll
            for (int w = 0; w < 4; ++w) {
                uint32_t m = adjm[tid][w] & visw[w];
                while (m) {
                    int u = (w << 5) + __ffs(m) - 1; m &= m - 1;
                    int o = s_order[u];
                    if (o < po) { po = o; par = u; }
                }
            }
            newly = (po < INF_);
            if (newly) {
                s_key[tid] = po * N_ + tid;
                atomicOr(&newlyw[tid >> 5], 1u << (tid & 31));
            }
        }
        __syncthreads();
        int myk = newly ? po * N_ + tid : 0x7FFFFFFF;
        int cnt = 0, rank = 0;
        #pragma unroll
        for (int w = 0; w < 4; ++w) {
            uint32_t m = newlyw[w];
            cnt += __popc(m);
            while (m) {
                int u = (w << 5) + __ffs(m) - 1; m &= m - 1;
                rank += (s_key[u] < myk);
            }
        }
        if (newly) {
            s_order[tid]  = counter + rank;
            s_parent[tid] = par;
            atomicOr(&visw[tid >> 5], 1u << (tid & 31));
        }
        counter += cnt;
        __syncthreads();
        if (cnt == 0) break;
    }

    // ---------- tree masks, degrees, pool weights ----------
    if (tid < 128) { tnbr[tid][0] = 0; tnbr[tid][1] = 0; tnbr[tid][2] = 0; tnbr[tid][3] = 0; }
    __syncthreads();
    if (tid < 128 && s_order[tid] > 0 && s_order[tid] < INF_) {
        int p = s_parent[tid];
        atomicOr(&tnbr[tid][p >> 5], 1u << (p & 31));
        atomicOr(&tnbr[p][tid >> 5], 1u << (tid & 31));
    }
    __syncthreads();
    if (tid < 128) {
        int d = 1 + __popc(tnbr[tid][0]) + __popc(tnbr[tid][1]) +
                    __popc(tnbr[tid][2]) + __popc(tnbr[tid][3]);
        s_inv[tid] = 1.0f / (float)d;
        int num = __popc(actw[0]) + __popc(actw[1]) + __popc(actw[2]) + __popc(actw[3]);
        int act = (actw[tid >> 5] >> (tid & 31)) & 1;
        s_wm[tid] = act ? (1.0f / (float)(num > 0 ? num : 1)) : 0.0f;
    }
    __syncthreads();

    // ---------- aggregation 1 (tree gather): xa = T̂norm @ x -> m1 B-frag layout ----------
    {
        const int v = tid >> 1, hf = tid & 1;
        float acc[64];
        const uint16_t* xr = &sbuf[v * 136 + hf * 64];
        #pragma unroll
        for (int i = 0; i < 64; i += 4) {
            uint64_t w = *reinterpret_cast<const uint64_t*>(xr + i);
            acc[i]   = b2f((uint16_t)w);
            acc[i+1] = b2f((uint16_t)(w >> 16));
            acc[i+2] = b2f((uint16_t)(w >> 32));
            acc[i+3] = b2f((uint16_t)(w >> 48));
        }
        #pragma unroll
        for (int wi = 0; wi < 4; ++wi) {
            uint32_t m = tnbr[v][wi];
            while (m) {
                int u = (wi << 5) + __ffs(m) - 1; m &= m - 1;
                const uint16_t* ur = &sbuf[u * 136 + hf * 64];
                #pragma unroll
                for (int i = 0; i < 64; i += 4) {
                    uint64_t w = *reinterpret_cast<const uint64_t*>(ur + i);
                    acc[i]   += b2f((uint16_t)w);
                    acc[i+1] += b2f((uint16_t)(w >> 16));
                    acc[i+2] += b2f((uint16_t)(w >> 32));
                    acc[i+3] += b2f((uint16_t)(w >> 48));
                }
            }
        }
        const float inv = s_inv[v];
        const int tnx = v >> 4, v15 = v & 15;
        #pragma unroll
        for (int kbl = 0; kbl < 2; ++kbl) {
            int kb = hf * 2 + kbl;
            #pragma unroll
            for (int qq = 0; qq < 4; ++qq) {
                int lo = kbl * 32 + qq * 8;
                u32x4 w;
                w[0] = pack2(acc[lo  ] * inv, acc[lo+1] * inv);
                w[1] = pack2(acc[lo+2] * inv, acc[lo+3] * inv);
                w[2] = pack2(acc[lo+4] * inv, acc[lo+5] * inv);
                w[3] = pack2(acc[lo+6] * inv, acc[lo+7] * inv);
                *reinterpret_cast<u32x4*>(
                    &sbuf[17408 + (((tnx * 4 + kb) * 64) + qq * 16 + v15) * 8]) = w;
            }
        }
    }
    __syncthreads();

    // ---------- matmul1 (swapped): h1^T = W1^T @ xa^T, MFMA 16x16x32 ----------
    // wave owns H-tiles tm = wid*4..+3, all 8 node-tiles. C lane: m=h (4 consec), n=node.
    {
        f32x4 acc1[4][8];
        #pragma unroll
        for (int j = 0; j < 4; ++j)
            #pragma unroll
            for (int t = 0; t < 8; ++t) acc1[j][t] = (f32x4){0.f, 0.f, 0.f, 0.f};
        const bf16x8* wsA = reinterpret_cast<const bf16x8*>(ws);
        for (int kb = 0; kb < 4; ++kb) {
            bf16x8 afr[4], bfr[8];
            #pragma unroll
            for (int j = 0; j < 4; ++j)
                afr[j] = wsA[((wid * 4 + j) * 4 + kb) * 64 + lane];
            #pragma unroll
            for (int t = 0; t < 8; ++t)
                bfr[t] = *reinterpret_cast<const bf16x8*>(
                    &sbuf[17408 + ((t * 4 + kb) * 64 + lane) * 8]);
            #pragma unroll
            for (int j = 0; j < 4; ++j)
                #pragma unroll
                for (int t = 0; t < 8; ++t)
                    acc1[j][t] = __builtin_amdgcn_mfma_f32_16x16x32_bf16(
                        afr[j], bfr[t], acc1[j][t], 0, 0, 0);
        }
        __syncthreads();   // xa reads done; write h1 (bias+relu) into m2 A-frag layout
        #pragma unroll
        for (int j = 0; j < 4; ++j) {
            int tm = wid * 4 + j;
            int m0 = tm * 16 + q * 4;
            f32x4 bb = *reinterpret_cast<const f32x4*>(&s_b1[m0]);
            int kbh = tm >> 1;
            int sl  = l15 + 16 * ((2 * tm + (q >> 1)) & 3);
            #pragma unroll
            for (int t = 0; t < 8; ++t) {
                f32x4 v = acc1[j][t];
                float v0 = fmaxf(v[0] + bb[0], 0.f), v1 = fmaxf(v[1] + bb[1], 0.f);
                float v2 = fmaxf(v[2] + bb[2], 0.f), v3 = fmaxf(v[3] + bb[3], 0.f);
                u32x2 w; w[0] = pack2(v0, v1); w[1] = pack2(v2, v3);
                *reinterpret_cast<u32x2*>(
                    &sbuf[((t * 8 + kbh) * 64 + sl) * 8 + (q & 1) * 4]) = w;
            }
        }
    }
    __syncthreads();

    // ---------- matmul2: M2 = h1 @ W2 ----------
    // wave owns H-out tiles tn = wid*4..+3, all 8 node-tiles. C lane: m=node (4 consec), n=h.
    {
        f32x4 acc2[8][4];
        #pragma unroll
        for (int tm = 0; tm < 8; ++tm)
            #pragma unroll
            for (int j = 0; j < 4; ++j) acc2[tm][j] = (f32x4){0.f, 0.f, 0.f, 0.f};
        const bf16x8* wsB = reinterpret_cast<const bf16x8*>(ws + 32768);
        for (int kb = 0; kb < 8; ++kb) {
            bf16x8 a2[8], bfr[4];
            #pragma unroll
            for (int tm = 0; tm < 8; ++tm)
                a2[tm] = *reinterpret_cast<const bf16x8*>(
                    &sbuf[((tm * 8 + kb) * 64 + lane) * 8]);
            #pragma unroll
            for (int j = 0; j < 4; ++j)
                bfr[j] = wsB[((wid * 4 + j) * 8 + kb) * 64 + lane];
            #pragma unroll
            for (int tm = 0; tm < 8; ++tm)
                #pragma unroll
                for (int j = 0; j < 4; ++j)
                    acc2[tm][j] = __builtin_amdgcn_mfma_f32_16x16x32_bf16(
                        a2[tm], bfr[j], acc2[tm][j], 0, 0, 0);
        }
        __syncthreads();   // h1 reads done; write M2 into agg2 B-frag layout (no bias yet)
        #pragma unroll
        for (int tm = 0; tm < 8; ++tm) {
            int kbh = tm >> 1;
            int sl  = l15 + 16 * ((2 * tm + (q >> 1)) & 3);
            #pragma unroll
            for (int j = 0; j < 4; ++j) {
                int tn = wid * 4 + j;
                f32x4 v = acc2[tm][j];
                u32x2 w; w[0] = pack2(v[0], v[1]); w[1] = pack2(v[2], v[3]);
                *reinterpret_cast<u32x2*>(
                    &sbuf[((tn * 4 + kbh) * 64 + sl) * 8 + (q & 1) * 4]) = w;
            }
        }
    }
    __syncthreads();

    // ---------- aggregation 2 via MFMA: AGG2 = T̂ @ M2; fused scale+bias+relu+mask+pool ----------
    // wave owns H-col tiles tn = wid*4..+3, all 8 v-tiles. A = T̂ frags built from bitmasks.
    {
        f32x4 acc3[8][4];
        #pragma unroll
        for (int tm = 0; tm < 8; ++tm)
            #pragma unroll
            for (int j = 0; j < 4; ++j) acc3[tm][j] = (f32x4){0.f, 0.f, 0.f, 0.f};
        for (int kb = 0; kb < 4; ++kb) {
            bf16x8 a3[8], bfr[4];
            #pragma unroll
            for (int tm = 0; tm < 8; ++tm) {
                int v = tm * 16 + l15;
                uint32_t word = tnbr[v][kb];
                uint32_t by = (word >> (q * 8)) & 0xFFu;
                if ((v >> 3) == kb * 4 + q) by |= 1u << (v & 7);
                u32x4 p;
                #pragma unroll
                for (int pp = 0; pp < 4; ++pp)
                    p[pp] = (((by >> (2 * pp)) & 1u) ? 0x3F80u : 0u) |
                            (((by >> (2 * pp + 1)) & 1u) ? 0x3F800000u : 0u);
                a3[tm] = __builtin_bit_cast(bf16x8, p);
            }
            #pragma unroll
            for (int j = 0; j < 4; ++j)
                bfr[j] = *reinterpret_cast<const bf16x8*>(
                    &sbuf[(((wid * 4 + j) * 4 + kb) * 64 + lane) * 8]);
            #pragma unroll
            for (int tm = 0; tm < 8; ++tm)
                #pragma unroll
                for (int j = 0; j < 4; ++j)
                    acc3[tm][j] = __builtin_amdgcn_mfma_f32_16x16x32_bf16(
                        a3[tm], bfr[j], acc3[tm][j], 0, 0, 0);
        }
        float ps[4] = {0.f, 0.f, 0.f, 0.f};
        #pragma unroll
        for (int tm = 0; tm < 8; ++tm) {
            int v0 = tm * 16 + q * 4;
            f32x4 iv = *reinterpret_cast<const f32x4*>(&s_inv[v0]);
            f32x4 wm = *reinterpret_cast<const f32x4*>(&s_wm[v0]);
            #pragma unroll
            for (int j = 0; j < 4; ++j) {
                float bc = s_b2[(wid * 4 + j) * 16 + l15];
                f32x4 a = acc3[tm][j];
                #pragma unroll
                for (int r = 0; r < 4; ++r)
                    ps[j] += fmaxf(fmaf(a[r], iv[r], bc), 0.f) * wm[r];
            }
        }
        #pragma unroll
        for (int j = 0; j < 4; ++j) {
            ps[j] += __shfl_xor(ps[j], 16);
            ps[j] += __shfl_xor(ps[j], 32);
        }
        if (q == 0) {
            #pragma unroll
            for (int j = 0; j < 4; ++j)
                s_g[(wid * 4 + j) * 16 + l15] = ps[j];
        }
    }
    __syncthreads();

    // ---------- heads ----------
    if (tid < 128) {
        const int which = tid >> 6, l = tid & 63;
        const float* W    = which ? Wlv : Wmu;
        const float* bias = which ? blv : bmu;
        float acch = 0.f;
        for (int cc = 0; cc < H_; ++cc)
            acch = fmaf(s_g[cc], W[cc * L_ + l], acch);
        out[(size_t)which * B_ * L_ + (size_t)b * L_ + l] = acch + bias[l];
    }
}

extern "C" void kernel_launch(void* const* d_in, const int* in_sizes, int n_in,
                              void* d_out, int out_size, void* d_ws, size_t ws_size,
                              hipStream_t stream) {
    const float* x   = (const float*)d_in[0];
    const float* adj = (const float*)d_in[1];
    const float* W1  = (const float*)d_in[2];
    const float* b1  = (const float*)d_in[3];
    const float* W2  = (const float*)d_in[4];
    const float* b2  = (const float*)d_in[5];
    const float* Wmu = (const float*)d_in[6];
    const float* bmu = (const float*)d_in[7];
    const float* Wlv = (const float*)d_in[8];
    const float* blv = (const float*)d_in[9];
    float* out = (float*)d_out;
    uint16_t* ws = (uint16_t*)d_ws;

    hipLaunchKernelGGL(prep_weights, dim3(48), dim3(256), 0, stream, W1, W2, ws);
    hipLaunchKernelGGL(tree_encoder_kernel, dim3(B_), dim3(256), 0, stream,
                       x, adj, ws, b1, b2, Wmu, bmu, Wlv, blv, out);
}